// Round 16
// baseline (49.216 us; speedup 1.0000x reference)
//
#include <hip/hip_runtime.h>
#include <math.h>

#define NL 371
#define LUTN 1024            // f32 float4 nodes; 16 KB LDS
#define NPIX (1024*1024)
#define NB 8
#define K1B 256              // minmax blocks per batch (8.25 blk/CU w/ LUT blocks)
#define K2B 256              // K2 blocks per batch (8 blocks/CU -> 100% occ)
#define NBIN 1024            // v-occupancy bins over [VLO, VLO+16)
#define VLO -8.0f
#define BINSCALE 64.0f       // NBIN/16
#define WV 0.015625f         // bin width = 2^-6 (exact)
#define STRESS_MAG 72000000.0f

__device__ __forceinline__ void lut_interp(const float4* slut, float s,
                                           float& i0, float& i1, float& i2) {
    float t = s * (float)(LUTN - 1);
    int j = (int)t;
    j = min(j, LUTN - 2);
    float fr = t - (float)j;
    float4 A = slut[j];
    float4 B = slut[j + 1];
    i0 = fmaf(fr, B.x - A.x, A.x);
    i1 = fmaf(fr, B.y - A.y, A.y);
    i2 = fmaf(fr, B.z - A.z, A.z);
}

// K1: blocks [0, NB*K1B): per-batch min/max partials + v-bin occupancy bitmaps
//     (byte-flag scatter; PARALLEL 256-thread pack -> no serial tail).
//     blocks [NB*K1B, +64): build the 1024-node f32 LUT (16-way lambda split).
__global__ __launch_bounds__(256) void k_stage1(const float4* __restrict__ x,
                                                const float* __restrict__ w,
                                                float4* __restrict__ lutg,
                                                float2* __restrict__ partials,
                                                unsigned* __restrict__ bitmaps) {
    __shared__ unsigned ubuf[2272];   // union: lut path 2252 dwords; mm path 264
    const int tid = threadIdx.x;
    const int bx  = blockIdx.x;

    if (bx < NB * K1B) {
        // ---- min/max + occupancy ----
        unsigned* sflag = ubuf;                 // 256 dwords = 1024 byte-flags
        float* smn = (float*)(ubuf + 256);
        float* smx = smn + 4;
        sflag[tid] = 0u;
        __syncthreads();
        int b = bx >> 8, blk = bx & 255;
        const float4* p = x + (size_t)b * (NPIX / 4);
        unsigned char* f = (unsigned char*)sflag;
        float mn = 3.4e38f, mx = -3.4e38f;
        #pragma unroll 2
        for (int i = blk * 256 + tid; i < NPIX / 4; i += K1B * 256) {
            float4 v = p[i];
            mn = fminf(mn, fminf(fminf(v.x, v.y), fminf(v.z, v.w)));
            mx = fmaxf(mx, fmaxf(fmaxf(v.x, v.y), fmaxf(v.z, v.w)));
            int b0 = min(NBIN - 1, max(0, (int)((v.x - VLO) * BINSCALE)));
            int b1 = min(NBIN - 1, max(0, (int)((v.y - VLO) * BINSCALE)));
            int b2 = min(NBIN - 1, max(0, (int)((v.z - VLO) * BINSCALE)));
            int b3 = min(NBIN - 1, max(0, (int)((v.w - VLO) * BINSCALE)));
            f[b0] = 1; f[b1] = 1; f[b2] = 1; f[b3] = 1;
        }
        for (int off = 32; off >= 1; off >>= 1) {
            mn = fminf(mn, __shfl_down(mn, off));
            mx = fmaxf(mx, __shfl_down(mx, off));
        }
        int wid = tid >> 6;
        if ((tid & 63) == 0) { smn[wid] = mn; smx[wid] = mx; }
        __syncthreads();     // flags + smn/smx visible
        // parallel pack: thread t extracts 4 byte-flags (dword t) into a nibble
        // at bit 4*(t&7); 3 shfl-ORs combine 8 threads -> one bitmap dword.
        {
            unsigned d = sflag[tid];
            unsigned nib = (d & 1u) | ((d >> 7) & 2u) | ((d >> 14) & 4u)
                         | ((d >> 21) & 8u);
            unsigned part = nib << (4 * (tid & 7));
            part |= __shfl_down(part, 4);
            part |= __shfl_down(part, 2);
            part |= __shfl_down(part, 1);
            if ((tid & 7) == 0)
                bitmaps[(size_t)(b * K1B + blk) * 32 + (tid >> 3)] = part;
        }
        if (tid == 0) {
            for (int k = 1; k < 4; ++k) { mn = fminf(mn, smn[k]); mx = fmaxf(mx, smx[k]); }
            partials[b * K1B + blk] = make_float2(mn, mx);
        }
    } else {
        // ---- LUT build: f_c(s) = sum_i w[i][c]*0.5*(1-cos(2pi*k_rev[i]*s)) ----
        float* kw = (float*)ubuf;
        float* w0 = kw + NL; float* w1 = w0 + NL; float* w2 = w1 + NL;
        float* rr = w2 + NL;                    // 768 floats
        const float coef_rev = (float)(0.01 * 3.5e-12 / 1e-9) * STRESS_MAG; // ~2520 rev
        for (int i = tid; i < NL; i += 256) {
            float lam = 390.0f + (float)i;      // linspace(390,760,371), step 1.0
            kw[i] = coef_rev / lam;
            w0[i] = w[i * 3 + 0]; w1[i] = w[i * 3 + 1]; w2[i] = w[i * 3 + 2];
        }
        __syncthreads();
        int jj = tid & 15, part = tid >> 4;     // 16 j x 16 lambda-parts
        int j  = (bx - NB * K1B) * 16 + jj;     // 0..1023
        float s = (float)j * (1.0f / (float)(LUTN - 1));
        float a0 = 0.f, a1 = 0.f, a2 = 0.f;
        for (int i = part; i < NL; i += 16) {
            float r = kw[i] * s;                // revolutions, <= ~6.6
            r = r - floorf(r);
            float c = __builtin_amdgcn_cosf(r); // cos(2*pi*r)
            float t = fmaf(-0.5f, c, 0.5f);
            a0 = fmaf(w0[i], t, a0); a1 = fmaf(w1[i], t, a1); a2 = fmaf(w2[i], t, a2);
        }
        rr[tid] = a0; rr[256 + tid] = a1; rr[512 + tid] = a2;
        __syncthreads();
        if (part == 0) {
            float s0 = 0.f, s1 = 0.f, s2 = 0.f;
            for (int p2 = 0; p2 < 16; ++p2) {
                s0 += rr[p2 * 16 + jj];
                s1 += rr[256 + p2 * 16 + jj];
                s2 += rr[512 + p2 * 16 + jj];
            }
            lutg[j] = make_float4(s0, s1, s2, 0.0f);
        }
    }
}

// k_const: one block per batch. Reduce K1B partials -> mn/mx; OR bitmaps
// (256-thr parallel); scan occupied bins x LUT -> isoM. Emit consts per batch.
__global__ __launch_bounds__(256) void k_const(const float4* __restrict__ lutg,
                                               const float2* __restrict__ partials,
                                               const unsigned* __restrict__ bitmaps,
                                               float4* __restrict__ consts) {
    __shared__ float4 slut[LUTN];
    __shared__ unsigned soccp[8][32];
    __shared__ unsigned socc[32];
    __shared__ float rmn[4], rmx[4], red[8];
    const int tid = threadIdx.x;
    const int b = blockIdx.x;
    for (int i = tid; i < LUTN; i += 256) slut[i] = lutg[i];
    // parallel OR: thread (p,k)=(tid>>5, tid&31) ORs blocks p, p+8, ...
    {
        int p = tid >> 5, k = tid & 31;
        unsigned m = 0;
        for (int blk = p; blk < K1B; blk += 8)
            m |= bitmaps[(size_t)(b * K1B + blk) * 32 + k];
        soccp[p][k] = m;
    }
    // all 256 threads reduce one partial each (K1B == 256)
    {
        float2 pm = partials[b * K1B + tid];
        float mn = pm.x, mx = pm.y;
        for (int off = 32; off >= 1; off >>= 1) {
            mn = fminf(mn, __shfl_down(mn, off));
            mx = fmaxf(mx, __shfl_down(mx, off));
        }
        if ((tid & 63) == 0) { rmn[tid >> 6] = mn; rmx[tid >> 6] = mx; }
    }
    __syncthreads();
    if (tid < 32) {
        unsigned m = 0;
        for (int p = 0; p < 8; ++p) m |= soccp[p][tid];
        socc[tid] = m;
    }
    __syncthreads();
    float mn = fminf(fminf(rmn[0], rmn[1]), fminf(rmn[2], rmn[3]));
    float mx = fmaxf(fmaxf(rmx[0], rmx[1]), fmaxf(rmx[2], rmx[3]));
    float inv = 1.0f / (mx - mn);

    float mloc = 0.0f;
    for (int bin = tid; bin < NBIN; bin += 256) {
        if ((socc[bin >> 5] >> (bin & 31)) & 1u) {
            float vlo = VLO + (float)bin * WV;
            float sa = fminf(1.0f, fmaxf(0.0f, (vlo - mn) * inv));
            float sb = fminf(1.0f, fmaxf(0.0f, (vlo + WV - mn) * inv));
            float i0, i1, i2;
            lut_interp(slut, sa, i0, i1, i2);
            mloc = fmaxf(mloc, fmaxf(fmaxf(i0, i1), i2));
            lut_interp(slut, sb, i0, i1, i2);
            mloc = fmaxf(mloc, fmaxf(fmaxf(i0, i1), i2));
            int ja = (int)(sa * (float)(LUTN - 1));
            int jb = min((int)(sb * (float)(LUTN - 1)), LUTN - 1);
            for (int j = ja + 1; j <= jb; ++j) {
                float4 A = slut[j];
                mloc = fmaxf(mloc, fmaxf(fmaxf(A.x, A.y), A.z));
            }
        }
    }
    for (int off = 32; off >= 1; off >>= 1)
        mloc = fmaxf(mloc, __shfl_down(mloc, off));
    int wid = tid >> 6;
    if ((tid & 63) == 0) red[4 + wid] = mloc;
    __syncthreads();
    if (tid == 0) {
        float isoM = fmaxf(fmaxf(red[4], red[5]), fmaxf(red[6], red[7]));
        consts[b] = make_float4(mn, inv, 1.0f / isoM, 0.0f);
    }
}

// K2: pure streaming: read x, write snorm, interp, write 3 iso planes.
__global__ __launch_bounds__(256) void k_stage2(const float4* __restrict__ x,
                                                const float4* __restrict__ lutg,
                                                const float4* __restrict__ consts,
                                                float4* __restrict__ snorm,
                                                float4* __restrict__ iso) {
    __shared__ float4 slut[LUTN];   // 16 KB
    const int tid = threadIdx.x;
    const int b = blockIdx.y;
    for (int i = tid; i < LUTN; i += 256) slut[i] = lutg[i];
    float4 cb = consts[b];
    float mn = cb.x, inv = cb.y, invIso = cb.z;
    __syncthreads();

    const float4* p = x + (size_t)b * (NPIX / 4);
    float4* qs = snorm + (size_t)b * (NPIX / 4);
    float4* q0 = iso + (size_t)(b * 3 + 0) * (NPIX / 4);
    float4* q1 = iso + (size_t)(b * 3 + 1) * (NPIX / 4);
    float4* q2 = iso + (size_t)(b * 3 + 2) * (NPIX / 4);
    for (int i = blockIdx.x * 256 + tid; i < NPIX / 4; i += K2B * 256) {
        float4 v = p[i];
        float4 s;
        s.x = (v.x - mn) * inv; s.y = (v.y - mn) * inv;
        s.z = (v.z - mn) * inv; s.w = (v.w - mn) * inv;
        qs[i] = s;
        float4 r0, r1, r2;
        float i0, i1, i2;
        lut_interp(slut, s.x, i0, i1, i2);
        r0.x = i0 * invIso; r1.x = i1 * invIso; r2.x = i2 * invIso;
        lut_interp(slut, s.y, i0, i1, i2);
        r0.y = i0 * invIso; r1.y = i1 * invIso; r2.y = i2 * invIso;
        lut_interp(slut, s.z, i0, i1, i2);
        r0.z = i0 * invIso; r1.z = i1 * invIso; r2.z = i2 * invIso;
        lut_interp(slut, s.w, i0, i1, i2);
        r0.w = i0 * invIso; r1.w = i1 * invIso; r2.w = i2 * invIso;
        q0[i] = r0; q1[i] = r1; q2[i] = r2;
    }
}

extern "C" void kernel_launch(void* const* d_in, const int* in_sizes, int n_in,
                              void* d_out, int out_size, void* d_ws, size_t ws_size,
                              hipStream_t stream) {
    const float4* x = (const float4*)d_in[0];   // [8,1,1024,1024] f32
    const float*  w = (const float*)d_in[1];    // [371,3] f32

    float* out    = (float*)d_out;
    float4* iso   = (float4*)out;                               // 8*3*1M f32
    float4* snorm = (float4*)(out + (size_t)NB * 3 * NPIX);     // 8*1M f32

    float4*   lutg     = (float4*)d_ws;                                    // 16 KB
    float2*   partials = (float2*)((char*)d_ws + 16384);                   // 16 KB
    unsigned* bitmaps  = (unsigned*)((char*)d_ws + 16384 + 16384);         // 256 KB
    float4*   consts   = (float4*)((char*)d_ws + 16384 + 16384 + 262144);  // 128 B

    k_stage1<<<dim3(NB * K1B + LUTN / 16), dim3(256), 0, stream>>>(
        x, w, lutg, partials, bitmaps);
    k_const<<<dim3(NB), dim3(256), 0, stream>>>(lutg, partials, bitmaps, consts);
    k_stage2<<<dim3(K2B, NB), dim3(256), 0, stream>>>(
        x, lutg, consts, snorm, iso);
}

// Round 17
// 44.914 us; speedup vs baseline: 1.0958x; 1.0958x over previous
//
#include <hip/hip_runtime.h>
#include <math.h>

#define NL 371
#define LUTN 512             // f32 float4 nodes; 8 KB LDS (2 stage iters in K2)
#define NPIX (1024*1024)
#define NB 8
#define K1B 64               // minmax/occupancy blocks per batch
#define K2B 256              // K2 blocks per batch (8 blocks/CU -> 100% occ)
#define NBIN 1024            // v-occupancy bins over [VLO, VLO+16)
#define VLO -8.0f
#define BINSCALE 64.0f       // NBIN/16
#define WV 0.015625f         // bin width = 2^-6 (exact)
#define STRESS_MAG 72000000.0f

__device__ __forceinline__ void lut_interp(const float4* slut, float s,
                                           float& i0, float& i1, float& i2) {
    float t = s * (float)(LUTN - 1);
    int j = (int)t;
    j = min(j, LUTN - 2);
    float fr = t - (float)j;
    float4 A = slut[j];
    float4 B = slut[j + 1];
    i0 = fmaf(fr, B.x - A.x, A.x);
    i1 = fmaf(fr, B.y - A.y, A.y);
    i2 = fmaf(fr, B.z - A.z, A.z);
}

// K1: blocks [0, NB*K1B): per-batch min/max partials + v-bin occupancy bitmaps.
//     blocks [NB*K1B, +32): build the 512-node f32 LUT (16-way lambda split).
__global__ __launch_bounds__(256) void k_stage1(const float4* __restrict__ x,
                                                const float* __restrict__ w,
                                                float4* __restrict__ lutg,
                                                float2* __restrict__ partials,
                                                unsigned* __restrict__ bitmaps) {
    __shared__ unsigned ubuf[2272];   // union: lut path 2252 dwords; mm path 264
    const int tid = threadIdx.x;
    const int bx  = blockIdx.x;

    if (bx < NB * K1B) {
        // ---- min/max + occupancy (byte-flag scatter, 2x unrolled loads) ----
        unsigned* sflag = ubuf;                 // 256 dwords = 1024 byte-flags
        float* smn = (float*)(ubuf + 256);
        float* smx = smn + 4;
        sflag[tid] = 0u;
        __syncthreads();
        int b = bx >> 6, blk = bx & 63;
        const float4* p = x + (size_t)b * (NPIX / 4);
        unsigned char* f = (unsigned char*)sflag;
        float mn = 3.4e38f, mx = -3.4e38f;
        #pragma unroll 2
        for (int i = blk * 256 + tid; i < NPIX / 4; i += K1B * 256) {
            float4 v = p[i];
            mn = fminf(mn, fminf(fminf(v.x, v.y), fminf(v.z, v.w)));
            mx = fmaxf(mx, fmaxf(fmaxf(v.x, v.y), fmaxf(v.z, v.w)));
            int b0 = min(NBIN - 1, max(0, (int)((v.x - VLO) * BINSCALE)));
            int b1 = min(NBIN - 1, max(0, (int)((v.y - VLO) * BINSCALE)));
            int b2 = min(NBIN - 1, max(0, (int)((v.z - VLO) * BINSCALE)));
            int b3 = min(NBIN - 1, max(0, (int)((v.w - VLO) * BINSCALE)));
            f[b0] = 1; f[b1] = 1; f[b2] = 1; f[b3] = 1;
        }
        for (int off = 32; off >= 1; off >>= 1) {
            mn = fminf(mn, __shfl_down(mn, off));
            mx = fmaxf(mx, __shfl_down(mx, off));
        }
        int wid = tid >> 6;
        if ((tid & 63) == 0) { smn[wid] = mn; smx[wid] = mx; }
        __syncthreads();     // flags + smn/smx visible
        if (tid < 32) {
            unsigned m = 0;
            for (int k = 0; k < 32; ++k) m |= (f[tid * 32 + k] ? 1u : 0u) << k;
            bitmaps[(size_t)(b * K1B + blk) * 32 + tid] = m;
        }
        if (tid == 0) {
            for (int k = 1; k < 4; ++k) { mn = fminf(mn, smn[k]); mx = fmaxf(mx, smx[k]); }
            partials[b * K1B + blk] = make_float2(mn, mx);
        }
    } else {
        // ---- LUT build: f_c(s) = sum_i w[i][c]*0.5*(1-cos(2pi*k_rev[i]*s)) ----
        float* kw = (float*)ubuf;
        float* w0 = kw + NL; float* w1 = w0 + NL; float* w2 = w1 + NL;
        float* rr = w2 + NL;                    // 768 floats
        const float coef_rev = (float)(0.01 * 3.5e-12 / 1e-9) * STRESS_MAG; // ~2520 rev
        for (int i = tid; i < NL; i += 256) {
            float lam = 390.0f + (float)i;      // linspace(390,760,371), step 1.0
            kw[i] = coef_rev / lam;
            w0[i] = w[i * 3 + 0]; w1[i] = w[i * 3 + 1]; w2[i] = w[i * 3 + 2];
        }
        __syncthreads();
        int jj = tid & 15, part = tid >> 4;     // 16 j x 16 lambda-parts
        int j  = (bx - NB * K1B) * 16 + jj;     // 0..511
        float s = (float)j * (1.0f / (float)(LUTN - 1));
        float a0 = 0.f, a1 = 0.f, a2 = 0.f;
        for (int i = part; i < NL; i += 16) {
            float r = kw[i] * s;                // revolutions, <= ~6.6
            r = r - floorf(r);
            float c = __builtin_amdgcn_cosf(r); // cos(2*pi*r)
            float t = fmaf(-0.5f, c, 0.5f);
            a0 = fmaf(w0[i], t, a0); a1 = fmaf(w1[i], t, a1); a2 = fmaf(w2[i], t, a2);
        }
        rr[tid] = a0; rr[256 + tid] = a1; rr[512 + tid] = a2;
        __syncthreads();
        if (part == 0) {
            float s0 = 0.f, s1 = 0.f, s2 = 0.f;
            for (int p2 = 0; p2 < 16; ++p2) {
                s0 += rr[p2 * 16 + jj];
                s1 += rr[256 + p2 * 16 + jj];
                s2 += rr[512 + p2 * 16 + jj];
            }
            lutg[j] = make_float4(s0, s1, s2, 0.0f);
        }
    }
}

// k_const: one block per batch. Reduce partials -> mn/mx; OR bitmaps (256-thr
// parallel); scan occupied bins against the LUT -> isoM. Emit consts per batch.
__global__ __launch_bounds__(256) void k_const(const float4* __restrict__ lutg,
                                               const float2* __restrict__ partials,
                                               const unsigned* __restrict__ bitmaps,
                                               float4* __restrict__ consts) {
    __shared__ float4 slut[LUTN];
    __shared__ unsigned soccp[8][32];
    __shared__ unsigned socc[32];
    __shared__ float red[8];
    const int tid = threadIdx.x;
    const int b = blockIdx.x;
    for (int i = tid; i < LUTN; i += 256) slut[i] = lutg[i];
    // parallel OR: thread (p,k)=(tid>>5, tid&31) ORs blocks p, p+8, ..., p+56
    {
        int p = tid >> 5, k = tid & 31;
        unsigned m = 0;
        for (int blk = p; blk < K1B; blk += 8)
            m |= bitmaps[(size_t)(b * K1B + blk) * 32 + k];
        soccp[p][k] = m;
    }
    if (tid < 64) {
        float2 pm = partials[b * K1B + tid];
        float mn = pm.x, mx = pm.y;
        for (int off = 32; off >= 1; off >>= 1) {
            mn = fminf(mn, __shfl_down(mn, off));
            mx = fmaxf(mx, __shfl_down(mx, off));
        }
        if (tid == 0) { red[0] = mn; red[1] = mx; }
    }
    __syncthreads();
    if (tid < 32) {
        unsigned m = 0;
        for (int p = 0; p < 8; ++p) m |= soccp[p][tid];
        socc[tid] = m;
    }
    __syncthreads();
    float mn = red[0], mx = red[1];
    float inv = 1.0f / (mx - mn);

    float mloc = 0.0f;
    for (int bin = tid; bin < NBIN; bin += 256) {
        if ((socc[bin >> 5] >> (bin & 31)) & 1u) {
            float vlo = VLO + (float)bin * WV;
            float sa = fminf(1.0f, fmaxf(0.0f, (vlo - mn) * inv));
            float sb = fminf(1.0f, fmaxf(0.0f, (vlo + WV - mn) * inv));
            float i0, i1, i2;
            lut_interp(slut, sa, i0, i1, i2);
            mloc = fmaxf(mloc, fmaxf(fmaxf(i0, i1), i2));
            lut_interp(slut, sb, i0, i1, i2);
            mloc = fmaxf(mloc, fmaxf(fmaxf(i0, i1), i2));
            int ja = (int)(sa * (float)(LUTN - 1));
            int jb = min((int)(sb * (float)(LUTN - 1)), LUTN - 1);
            for (int j = ja + 1; j <= jb; ++j) {
                float4 A = slut[j];
                mloc = fmaxf(mloc, fmaxf(fmaxf(A.x, A.y), A.z));
            }
        }
    }
    for (int off = 32; off >= 1; off >>= 1)
        mloc = fmaxf(mloc, __shfl_down(mloc, off));
    int wid = tid >> 6;
    if ((tid & 63) == 0) red[4 + wid] = mloc;
    __syncthreads();
    if (tid == 0) {
        float isoM = fmaxf(fmaxf(red[4], red[5]), fmaxf(red[6], red[7]));
        consts[b] = make_float4(mn, inv, 1.0f / isoM, 0.0f);
    }
}

// K2: pure streaming: read x, write snorm, interp, write 3 iso planes.
__global__ __launch_bounds__(256) void k_stage2(const float4* __restrict__ x,
                                                const float4* __restrict__ lutg,
                                                const float4* __restrict__ consts,
                                                float4* __restrict__ snorm,
                                                float4* __restrict__ iso) {
    __shared__ float4 slut[LUTN];   // 8 KB
    const int tid = threadIdx.x;
    const int b = blockIdx.y;
    for (int i = tid; i < LUTN; i += 256) slut[i] = lutg[i];
    float4 cb = consts[b];
    float mn = cb.x, inv = cb.y, invIso = cb.z;
    __syncthreads();

    const float4* p = x + (size_t)b * (NPIX / 4);
    float4* qs = snorm + (size_t)b * (NPIX / 4);
    float4* q0 = iso + (size_t)(b * 3 + 0) * (NPIX / 4);
    float4* q1 = iso + (size_t)(b * 3 + 1) * (NPIX / 4);
    float4* q2 = iso + (size_t)(b * 3 + 2) * (NPIX / 4);
    for (int i = blockIdx.x * 256 + tid; i < NPIX / 4; i += K2B * 256) {
        float4 v = p[i];
        float4 s;
        s.x = (v.x - mn) * inv; s.y = (v.y - mn) * inv;
        s.z = (v.z - mn) * inv; s.w = (v.w - mn) * inv;
        qs[i] = s;
        float4 r0, r1, r2;
        float i0, i1, i2;
        lut_interp(slut, s.x, i0, i1, i2);
        r0.x = i0 * invIso; r1.x = i1 * invIso; r2.x = i2 * invIso;
        lut_interp(slut, s.y, i0, i1, i2);
        r0.y = i0 * invIso; r1.y = i1 * invIso; r2.y = i2 * invIso;
        lut_interp(slut, s.z, i0, i1, i2);
        r0.z = i0 * invIso; r1.z = i1 * invIso; r2.z = i2 * invIso;
        lut_interp(slut, s.w, i0, i1, i2);
        r0.w = i0 * invIso; r1.w = i1 * invIso; r2.w = i2 * invIso;
        q0[i] = r0; q1[i] = r1; q2[i] = r2;
    }
}

extern "C" void kernel_launch(void* const* d_in, const int* in_sizes, int n_in,
                              void* d_out, int out_size, void* d_ws, size_t ws_size,
                              hipStream_t stream) {
    const float4* x = (const float4*)d_in[0];   // [8,1,1024,1024] f32
    const float*  w = (const float*)d_in[1];    // [371,3] f32

    float* out    = (float*)d_out;
    float4* iso   = (float4*)out;                               // 8*3*1M f32
    float4* snorm = (float4*)(out + (size_t)NB * 3 * NPIX);     // 8*1M f32

    float4*   lutg     = (float4*)d_ws;                                   // 8 KB
    float2*   partials = (float2*)((char*)d_ws + 8192);                   // 4 KB
    unsigned* bitmaps  = (unsigned*)((char*)d_ws + 8192 + 4096);          // 64 KB
    float4*   consts   = (float4*)((char*)d_ws + 8192 + 4096 + 65536);    // 128 B

    k_stage1<<<dim3(NB * K1B + LUTN / 16), dim3(256), 0, stream>>>(
        x, w, lutg, partials, bitmaps);
    k_const<<<dim3(NB), dim3(256), 0, stream>>>(lutg, partials, bitmaps, consts);
    k_stage2<<<dim3(K2B, NB), dim3(256), 0, stream>>>(
        x, lutg, consts, snorm, iso);
}

// Round 18
// 44.480 us; speedup vs baseline: 1.1065x; 1.0098x over previous
//
#include <hip/hip_runtime.h>
#include <math.h>

#define NL 371
#define LUTN 256             // f32 float4 nodes; 4 KB LDS (single stage iter)
#define NPIX (1024*1024)
#define NB 8
#define K1B 64               // minmax/occupancy blocks per batch
#define K2B 256              // K2 blocks per batch (8 blocks/CU -> 100% occ)
#define NBIN 1024            // v-occupancy bins over [VLO, VLO+16)
#define VLO -8.0f
#define BINSCALE 64.0f       // NBIN/16
#define WV 0.015625f         // bin width = 2^-6 (exact)
#define STRESS_MAG 72000000.0f

__device__ __forceinline__ void lut_interp(const float4* slut, float s,
                                           float& i0, float& i1, float& i2) {
    float t = s * (float)(LUTN - 1);
    int j = (int)t;
    j = min(j, LUTN - 2);
    float fr = t - (float)j;
    float4 A = slut[j];
    float4 B = slut[j + 1];
    i0 = fmaf(fr, B.x - A.x, A.x);
    i1 = fmaf(fr, B.y - A.y, A.y);
    i2 = fmaf(fr, B.z - A.z, A.z);
}

// K1: blocks [0, NB*K1B): per-batch min/max partials + v-bin occupancy bitmaps.
//     blocks [NB*K1B, +16): build the 256-node f32 LUT (16-way lambda split).
__global__ __launch_bounds__(256) void k_stage1(const float4* __restrict__ x,
                                                const float* __restrict__ w,
                                                float4* __restrict__ lutg,
                                                float2* __restrict__ partials,
                                                unsigned* __restrict__ bitmaps) {
    __shared__ unsigned ubuf[2272];   // union: lut path 2252 dwords; mm path 264
    const int tid = threadIdx.x;
    const int bx  = blockIdx.x;

    if (bx < NB * K1B) {
        // ---- min/max + occupancy (byte-flag scatter, 2x unrolled loads) ----
        unsigned* sflag = ubuf;                 // 256 dwords = 1024 byte-flags
        float* smn = (float*)(ubuf + 256);
        float* smx = smn + 4;
        sflag[tid] = 0u;
        __syncthreads();
        int b = bx >> 6, blk = bx & 63;
        const float4* p = x + (size_t)b * (NPIX / 4);
        unsigned char* f = (unsigned char*)sflag;
        float mn = 3.4e38f, mx = -3.4e38f;
        #pragma unroll 2
        for (int i = blk * 256 + tid; i < NPIX / 4; i += K1B * 256) {
            float4 v = p[i];
            mn = fminf(mn, fminf(fminf(v.x, v.y), fminf(v.z, v.w)));
            mx = fmaxf(mx, fmaxf(fmaxf(v.x, v.y), fmaxf(v.z, v.w)));
            int b0 = min(NBIN - 1, max(0, (int)((v.x - VLO) * BINSCALE)));
            int b1 = min(NBIN - 1, max(0, (int)((v.y - VLO) * BINSCALE)));
            int b2 = min(NBIN - 1, max(0, (int)((v.z - VLO) * BINSCALE)));
            int b3 = min(NBIN - 1, max(0, (int)((v.w - VLO) * BINSCALE)));
            f[b0] = 1; f[b1] = 1; f[b2] = 1; f[b3] = 1;
        }
        for (int off = 32; off >= 1; off >>= 1) {
            mn = fminf(mn, __shfl_down(mn, off));
            mx = fmaxf(mx, __shfl_down(mx, off));
        }
        int wid = tid >> 6;
        if ((tid & 63) == 0) { smn[wid] = mn; smx[wid] = mx; }
        __syncthreads();     // flags + smn/smx visible
        if (tid < 32) {
            unsigned m = 0;
            for (int k = 0; k < 32; ++k) m |= (f[tid * 32 + k] ? 1u : 0u) << k;
            bitmaps[(size_t)(b * K1B + blk) * 32 + tid] = m;
        }
        if (tid == 0) {
            for (int k = 1; k < 4; ++k) { mn = fminf(mn, smn[k]); mx = fmaxf(mx, smx[k]); }
            partials[b * K1B + blk] = make_float2(mn, mx);
        }
    } else {
        // ---- LUT build: f_c(s) = sum_i w[i][c]*0.5*(1-cos(2pi*k_rev[i]*s)) ----
        float* kw = (float*)ubuf;
        float* w0 = kw + NL; float* w1 = w0 + NL; float* w2 = w1 + NL;
        float* rr = w2 + NL;                    // 768 floats
        const float coef_rev = (float)(0.01 * 3.5e-12 / 1e-9) * STRESS_MAG; // ~2520 rev
        for (int i = tid; i < NL; i += 256) {
            float lam = 390.0f + (float)i;      // linspace(390,760,371), step 1.0
            kw[i] = coef_rev / lam;
            w0[i] = w[i * 3 + 0]; w1[i] = w[i * 3 + 1]; w2[i] = w[i * 3 + 2];
        }
        __syncthreads();
        int jj = tid & 15, part = tid >> 4;     // 16 j x 16 lambda-parts
        int j  = (bx - NB * K1B) * 16 + jj;     // 0..255
        float s = (float)j * (1.0f / (float)(LUTN - 1));
        float a0 = 0.f, a1 = 0.f, a2 = 0.f;
        for (int i = part; i < NL; i += 16) {
            float r = kw[i] * s;                // revolutions, <= ~6.6
            r = r - floorf(r);
            float c = __builtin_amdgcn_cosf(r); // cos(2*pi*r)
            float t = fmaf(-0.5f, c, 0.5f);
            a0 = fmaf(w0[i], t, a0); a1 = fmaf(w1[i], t, a1); a2 = fmaf(w2[i], t, a2);
        }
        rr[tid] = a0; rr[256 + tid] = a1; rr[512 + tid] = a2;
        __syncthreads();
        if (part == 0) {
            float s0 = 0.f, s1 = 0.f, s2 = 0.f;
            for (int p2 = 0; p2 < 16; ++p2) {
                s0 += rr[p2 * 16 + jj];
                s1 += rr[256 + p2 * 16 + jj];
                s2 += rr[512 + p2 * 16 + jj];
            }
            lutg[j] = make_float4(s0, s1, s2, 0.0f);
        }
    }
}

// k_const: one block per batch. Reduce partials -> mn/mx; OR bitmaps (256-thr
// parallel); scan occupied bins against the LUT -> isoM. Emit consts per batch.
__global__ __launch_bounds__(256) void k_const(const float4* __restrict__ lutg,
                                               const float2* __restrict__ partials,
                                               const unsigned* __restrict__ bitmaps,
                                               float4* __restrict__ consts) {
    __shared__ float4 slut[LUTN];
    __shared__ unsigned soccp[8][32];
    __shared__ unsigned socc[32];
    __shared__ float red[8];
    const int tid = threadIdx.x;
    const int b = blockIdx.x;
    for (int i = tid; i < LUTN; i += 256) slut[i] = lutg[i];
    // parallel OR: thread (p,k)=(tid>>5, tid&31) ORs blocks p, p+8, ..., p+56
    {
        int p = tid >> 5, k = tid & 31;
        unsigned m = 0;
        for (int blk = p; blk < K1B; blk += 8)
            m |= bitmaps[(size_t)(b * K1B + blk) * 32 + k];
        soccp[p][k] = m;
    }
    if (tid < 64) {
        float2 pm = partials[b * K1B + tid];
        float mn = pm.x, mx = pm.y;
        for (int off = 32; off >= 1; off >>= 1) {
            mn = fminf(mn, __shfl_down(mn, off));
            mx = fmaxf(mx, __shfl_down(mx, off));
        }
        if (tid == 0) { red[0] = mn; red[1] = mx; }
    }
    __syncthreads();
    if (tid < 32) {
        unsigned m = 0;
        for (int p = 0; p < 8; ++p) m |= soccp[p][tid];
        socc[tid] = m;
    }
    __syncthreads();
    float mn = red[0], mx = red[1];
    float inv = 1.0f / (mx - mn);

    float mloc = 0.0f;
    for (int bin = tid; bin < NBIN; bin += 256) {
        if ((socc[bin >> 5] >> (bin & 31)) & 1u) {
            float vlo = VLO + (float)bin * WV;
            float sa = fminf(1.0f, fmaxf(0.0f, (vlo - mn) * inv));
            float sb = fminf(1.0f, fmaxf(0.0f, (vlo + WV - mn) * inv));
            float i0, i1, i2;
            lut_interp(slut, sa, i0, i1, i2);
            mloc = fmaxf(mloc, fmaxf(fmaxf(i0, i1), i2));
            lut_interp(slut, sb, i0, i1, i2);
            mloc = fmaxf(mloc, fmaxf(fmaxf(i0, i1), i2));
            int ja = (int)(sa * (float)(LUTN - 1));
            int jb = min((int)(sb * (float)(LUTN - 1)), LUTN - 1);
            for (int j = ja + 1; j <= jb; ++j) {
                float4 A = slut[j];
                mloc = fmaxf(mloc, fmaxf(fmaxf(A.x, A.y), A.z));
            }
        }
    }
    for (int off = 32; off >= 1; off >>= 1)
        mloc = fmaxf(mloc, __shfl_down(mloc, off));
    int wid = tid >> 6;
    if ((tid & 63) == 0) red[4 + wid] = mloc;
    __syncthreads();
    if (tid == 0) {
        float isoM = fmaxf(fmaxf(red[4], red[5]), fmaxf(red[6], red[7]));
        consts[b] = make_float4(mn, inv, 1.0f / isoM, 0.0f);
    }
}

// K2: pure streaming: read x, write snorm, interp, write 3 iso planes.
__global__ __launch_bounds__(256) void k_stage2(const float4* __restrict__ x,
                                                const float4* __restrict__ lutg,
                                                const float4* __restrict__ consts,
                                                float4* __restrict__ snorm,
                                                float4* __restrict__ iso) {
    __shared__ float4 slut[LUTN];   // 4 KB
    const int tid = threadIdx.x;
    const int b = blockIdx.y;
    if (tid < LUTN) slut[tid] = lutg[tid];      // single stage iteration
    float4 cb = consts[b];
    float mn = cb.x, inv = cb.y, invIso = cb.z;
    __syncthreads();

    const float4* p = x + (size_t)b * (NPIX / 4);
    float4* qs = snorm + (size_t)b * (NPIX / 4);
    float4* q0 = iso + (size_t)(b * 3 + 0) * (NPIX / 4);
    float4* q1 = iso + (size_t)(b * 3 + 1) * (NPIX / 4);
    float4* q2 = iso + (size_t)(b * 3 + 2) * (NPIX / 4);
    for (int i = blockIdx.x * 256 + tid; i < NPIX / 4; i += K2B * 256) {
        float4 v = p[i];
        float4 s;
        s.x = (v.x - mn) * inv; s.y = (v.y - mn) * inv;
        s.z = (v.z - mn) * inv; s.w = (v.w - mn) * inv;
        qs[i] = s;
        float4 r0, r1, r2;
        float i0, i1, i2;
        lut_interp(slut, s.x, i0, i1, i2);
        r0.x = i0 * invIso; r1.x = i1 * invIso; r2.x = i2 * invIso;
        lut_interp(slut, s.y, i0, i1, i2);
        r0.y = i0 * invIso; r1.y = i1 * invIso; r2.y = i2 * invIso;
        lut_interp(slut, s.z, i0, i1, i2);
        r0.z = i0 * invIso; r1.z = i1 * invIso; r2.z = i2 * invIso;
        lut_interp(slut, s.w, i0, i1, i2);
        r0.w = i0 * invIso; r1.w = i1 * invIso; r2.w = i2 * invIso;
        q0[i] = r0; q1[i] = r1; q2[i] = r2;
    }
}

extern "C" void kernel_launch(void* const* d_in, const int* in_sizes, int n_in,
                              void* d_out, int out_size, void* d_ws, size_t ws_size,
                              hipStream_t stream) {
    const float4* x = (const float4*)d_in[0];   // [8,1,1024,1024] f32
    const float*  w = (const float*)d_in[1];    // [371,3] f32

    float* out    = (float*)d_out;
    float4* iso   = (float4*)out;                               // 8*3*1M f32
    float4* snorm = (float4*)(out + (size_t)NB * 3 * NPIX);     // 8*1M f32

    float4*   lutg     = (float4*)d_ws;                                   // 4 KB
    float2*   partials = (float2*)((char*)d_ws + 4096);                   // 4 KB
    unsigned* bitmaps  = (unsigned*)((char*)d_ws + 4096 + 4096);          // 64 KB
    float4*   consts   = (float4*)((char*)d_ws + 4096 + 4096 + 65536);    // 128 B

    k_stage1<<<dim3(NB * K1B + LUTN / 16), dim3(256), 0, stream>>>(
        x, w, lutg, partials, bitmaps);
    k_const<<<dim3(NB), dim3(256), 0, stream>>>(lutg, partials, bitmaps, consts);
    k_stage2<<<dim3(K2B, NB), dim3(256), 0, stream>>>(
        x, lutg, consts, snorm, iso);
}

// Round 19
// 43.969 us; speedup vs baseline: 1.1193x; 1.0116x over previous
//
#include <hip/hip_runtime.h>
#include <math.h>

#define NL 371
#define LUTN 256             // f32 float4 nodes; 4 KB LDS (single stage iter)
#define NPIX (1024*1024)
#define NB 8
#define K1B 64               // minmax/occupancy blocks per batch
#define K2B 256              // K2 blocks per batch (8 blocks/CU -> 100% occ)
#define NBIN 1024            // v-occupancy bins over [VLO, VLO+16)
#define VLO -8.0f
#define BINSCALE 64.0f       // NBIN/16
#define WV 0.015625f         // bin width = 2^-6 (exact)
#define STRESS_MAG 72000000.0f

__device__ __forceinline__ void lut_interp(const float4* slut, float s,
                                           float& i0, float& i1, float& i2) {
    float t = s * (float)(LUTN - 1);
    int j = (int)t;
    j = min(j, LUTN - 2);
    float fr = t - (float)j;
    float4 A = slut[j];
    float4 B = slut[j + 1];
    i0 = fmaf(fr, B.x - A.x, A.x);
    i1 = fmaf(fr, B.y - A.y, A.y);
    i2 = fmaf(fr, B.z - A.z, A.z);
}

// K1: blocks [0, NB*K1B): per-batch min/max partials + v-bin occupancy bitmaps.
//     blocks [NB*K1B, +16): build the 256-node f32 LUT (16-way lambda split).
__global__ __launch_bounds__(256) void k_stage1(const float4* __restrict__ x,
                                                const float* __restrict__ w,
                                                float4* __restrict__ lutg,
                                                float2* __restrict__ partials,
                                                unsigned* __restrict__ bitmaps) {
    __shared__ unsigned ubuf[2272];   // union: lut path 2252 dwords; mm path 264
    const int tid = threadIdx.x;
    const int bx  = blockIdx.x;

    if (bx < NB * K1B) {
        // ---- min/max + occupancy (byte-flag scatter, 2x unrolled loads) ----
        unsigned* sflag = ubuf;                 // 256 dwords = 1024 byte-flags
        float* smn = (float*)(ubuf + 256);
        float* smx = smn + 4;
        sflag[tid] = 0u;
        __syncthreads();
        int b = bx >> 6, blk = bx & 63;
        const float4* p = x + (size_t)b * (NPIX / 4);
        unsigned char* f = (unsigned char*)sflag;
        float mn = 3.4e38f, mx = -3.4e38f;
        #pragma unroll 2
        for (int i = blk * 256 + tid; i < NPIX / 4; i += K1B * 256) {
            float4 v = p[i];
            mn = fminf(mn, fminf(fminf(v.x, v.y), fminf(v.z, v.w)));
            mx = fmaxf(mx, fmaxf(fmaxf(v.x, v.y), fmaxf(v.z, v.w)));
            int b0 = min(NBIN - 1, max(0, (int)((v.x - VLO) * BINSCALE)));
            int b1 = min(NBIN - 1, max(0, (int)((v.y - VLO) * BINSCALE)));
            int b2 = min(NBIN - 1, max(0, (int)((v.z - VLO) * BINSCALE)));
            int b3 = min(NBIN - 1, max(0, (int)((v.w - VLO) * BINSCALE)));
            f[b0] = 1; f[b1] = 1; f[b2] = 1; f[b3] = 1;
        }
        for (int off = 32; off >= 1; off >>= 1) {
            mn = fminf(mn, __shfl_down(mn, off));
            mx = fmaxf(mx, __shfl_down(mx, off));
        }
        int wid = tid >> 6;
        if ((tid & 63) == 0) { smn[wid] = mn; smx[wid] = mx; }
        __syncthreads();     // flags + smn/smx visible
        if (tid < 32) {
            unsigned m = 0;
            for (int k = 0; k < 32; ++k) m |= (f[tid * 32 + k] ? 1u : 0u) << k;
            bitmaps[(size_t)(b * K1B + blk) * 32 + tid] = m;
        }
        if (tid == 0) {
            for (int k = 1; k < 4; ++k) { mn = fminf(mn, smn[k]); mx = fmaxf(mx, smx[k]); }
            partials[b * K1B + blk] = make_float2(mn, mx);
        }
    } else {
        // ---- LUT build: f_c(s) = sum_i w[i][c]*0.5*(1-cos(2pi*k_rev[i]*s)) ----
        float* kw = (float*)ubuf;
        float* w0 = kw + NL; float* w1 = w0 + NL; float* w2 = w1 + NL;
        float* rr = w2 + NL;                    // 768 floats
        const float coef_rev = (float)(0.01 * 3.5e-12 / 1e-9) * STRESS_MAG; // ~2520 rev
        for (int i = tid; i < NL; i += 256) {
            float lam = 390.0f + (float)i;      // linspace(390,760,371), step 1.0
            kw[i] = coef_rev / lam;
            w0[i] = w[i * 3 + 0]; w1[i] = w[i * 3 + 1]; w2[i] = w[i * 3 + 2];
        }
        __syncthreads();
        int jj = tid & 15, part = tid >> 4;     // 16 j x 16 lambda-parts
        int j  = (bx - NB * K1B) * 16 + jj;     // 0..255
        float s = (float)j * (1.0f / (float)(LUTN - 1));
        float a0 = 0.f, a1 = 0.f, a2 = 0.f;
        for (int i = part; i < NL; i += 16) {
            float r = kw[i] * s;                // revolutions, <= ~6.6
            r = r - floorf(r);
            float c = __builtin_amdgcn_cosf(r); // cos(2*pi*r)
            float t = fmaf(-0.5f, c, 0.5f);
            a0 = fmaf(w0[i], t, a0); a1 = fmaf(w1[i], t, a1); a2 = fmaf(w2[i], t, a2);
        }
        rr[tid] = a0; rr[256 + tid] = a1; rr[512 + tid] = a2;
        __syncthreads();
        if (part == 0) {
            float s0 = 0.f, s1 = 0.f, s2 = 0.f;
            for (int p2 = 0; p2 < 16; ++p2) {
                s0 += rr[p2 * 16 + jj];
                s1 += rr[256 + p2 * 16 + jj];
                s2 += rr[512 + p2 * 16 + jj];
            }
            lutg[j] = make_float4(s0, s1, s2, 0.0f);
        }
    }
}

// k_const: one block per batch. Reduce partials -> mn/mx; OR bitmaps (256-thr
// parallel); scan occupied bins against the LUT -> isoM. Emit consts per batch.
__global__ __launch_bounds__(256) void k_const(const float4* __restrict__ lutg,
                                               const float2* __restrict__ partials,
                                               const unsigned* __restrict__ bitmaps,
                                               float4* __restrict__ consts) {
    __shared__ float4 slut[LUTN];
    __shared__ unsigned soccp[8][32];
    __shared__ unsigned socc[32];
    __shared__ float red[8];
    const int tid = threadIdx.x;
    const int b = blockIdx.x;
    for (int i = tid; i < LUTN; i += 256) slut[i] = lutg[i];
    // parallel OR: thread (p,k)=(tid>>5, tid&31) ORs blocks p, p+8, ..., p+56
    {
        int p = tid >> 5, k = tid & 31;
        unsigned m = 0;
        for (int blk = p; blk < K1B; blk += 8)
            m |= bitmaps[(size_t)(b * K1B + blk) * 32 + k];
        soccp[p][k] = m;
    }
    if (tid < 64) {
        float2 pm = partials[b * K1B + tid];
        float mn = pm.x, mx = pm.y;
        for (int off = 32; off >= 1; off >>= 1) {
            mn = fminf(mn, __shfl_down(mn, off));
            mx = fmaxf(mx, __shfl_down(mx, off));
        }
        if (tid == 0) { red[0] = mn; red[1] = mx; }
    }
    __syncthreads();
    if (tid < 32) {
        unsigned m = 0;
        for (int p = 0; p < 8; ++p) m |= soccp[p][tid];
        socc[tid] = m;
    }
    __syncthreads();
    float mn = red[0], mx = red[1];
    float inv = 1.0f / (mx - mn);

    float mloc = 0.0f;
    for (int bin = tid; bin < NBIN; bin += 256) {
        if ((socc[bin >> 5] >> (bin & 31)) & 1u) {
            float vlo = VLO + (float)bin * WV;
            float sa = fminf(1.0f, fmaxf(0.0f, (vlo - mn) * inv));
            float sb = fminf(1.0f, fmaxf(0.0f, (vlo + WV - mn) * inv));
            float i0, i1, i2;
            lut_interp(slut, sa, i0, i1, i2);
            mloc = fmaxf(mloc, fmaxf(fmaxf(i0, i1), i2));
            lut_interp(slut, sb, i0, i1, i2);
            mloc = fmaxf(mloc, fmaxf(fmaxf(i0, i1), i2));
            int ja = (int)(sa * (float)(LUTN - 1));
            int jb = min((int)(sb * (float)(LUTN - 1)), LUTN - 1);
            for (int j = ja + 1; j <= jb; ++j) {
                float4 A = slut[j];
                mloc = fmaxf(mloc, fmaxf(fmaxf(A.x, A.y), A.z));
            }
        }
    }
    for (int off = 32; off >= 1; off >>= 1)
        mloc = fmaxf(mloc, __shfl_down(mloc, off));
    int wid = tid >> 6;
    if ((tid & 63) == 0) red[4 + wid] = mloc;
    __syncthreads();
    if (tid == 0) {
        float isoM = fmaxf(fmaxf(red[4], red[5]), fmaxf(red[6], red[7]));
        consts[b] = make_float4(mn, inv, 1.0f / isoM, 0.0f);
    }
}

// K2: pure streaming: read x, write snorm, interp, write 3 iso planes.
__global__ __launch_bounds__(256) void k_stage2(const float4* __restrict__ x,
                                                const float4* __restrict__ lutg,
                                                const float4* __restrict__ consts,
                                                float4* __restrict__ snorm,
                                                float4* __restrict__ iso) {
    __shared__ float4 slut[LUTN];   // 4 KB
    const int tid = threadIdx.x;
    const int b = blockIdx.y;
    if (tid < LUTN) slut[tid] = lutg[tid];      // single stage iteration
    float4 cb = consts[b];
    float mn = cb.x, inv = cb.y, invIso = cb.z;
    __syncthreads();

    const float4* p = x + (size_t)b * (NPIX / 4);
    float4* qs = snorm + (size_t)b * (NPIX / 4);
    float4* q0 = iso + (size_t)(b * 3 + 0) * (NPIX / 4);
    float4* q1 = iso + (size_t)(b * 3 + 1) * (NPIX / 4);
    float4* q2 = iso + (size_t)(b * 3 + 2) * (NPIX / 4);
    for (int i = blockIdx.x * 256 + tid; i < NPIX / 4; i += K2B * 256) {
        float4 v = p[i];
        float4 s;
        s.x = (v.x - mn) * inv; s.y = (v.y - mn) * inv;
        s.z = (v.z - mn) * inv; s.w = (v.w - mn) * inv;
        qs[i] = s;
        float4 r0, r1, r2;
        float i0, i1, i2;
        lut_interp(slut, s.x, i0, i1, i2);
        r0.x = i0 * invIso; r1.x = i1 * invIso; r2.x = i2 * invIso;
        lut_interp(slut, s.y, i0, i1, i2);
        r0.y = i0 * invIso; r1.y = i1 * invIso; r2.y = i2 * invIso;
        lut_interp(slut, s.z, i0, i1, i2);
        r0.z = i0 * invIso; r1.z = i1 * invIso; r2.z = i2 * invIso;
        lut_interp(slut, s.w, i0, i1, i2);
        r0.w = i0 * invIso; r1.w = i1 * invIso; r2.w = i2 * invIso;
        q0[i] = r0; q1[i] = r1; q2[i] = r2;
    }
}

extern "C" void kernel_launch(void* const* d_in, const int* in_sizes, int n_in,
                              void* d_out, int out_size, void* d_ws, size_t ws_size,
                              hipStream_t stream) {
    const float4* x = (const float4*)d_in[0];   // [8,1,1024,1024] f32
    const float*  w = (const float*)d_in[1];    // [371,3] f32

    float* out    = (float*)d_out;
    float4* iso   = (float4*)out;                               // 8*3*1M f32
    float4* snorm = (float4*)(out + (size_t)NB * 3 * NPIX);     // 8*1M f32

    float4*   lutg     = (float4*)d_ws;                                   // 4 KB
    float2*   partials = (float2*)((char*)d_ws + 4096);                   // 4 KB
    unsigned* bitmaps  = (unsigned*)((char*)d_ws + 4096 + 4096);          // 64 KB
    float4*   consts   = (float4*)((char*)d_ws + 4096 + 4096 + 65536);    // 128 B

    k_stage1<<<dim3(NB * K1B + LUTN / 16), dim3(256), 0, stream>>>(
        x, w, lutg, partials, bitmaps);
    k_const<<<dim3(NB), dim3(256), 0, stream>>>(lutg, partials, bitmaps, consts);
    k_stage2<<<dim3(K2B, NB), dim3(256), 0, stream>>>(
        x, lutg, consts, snorm, iso);
}